// Round 3
// baseline (522.389 us; speedup 1.0000x reference)
//
#include <hip/hip_runtime.h>
#include <hip/hip_bf16.h>

typedef __attribute__((ext_vector_type(8))) short bf16x8;
typedef __attribute__((ext_vector_type(4))) float f32x4;
typedef unsigned int u32;
typedef unsigned short u16;

#define NB 65536
#define NKD 512
#define NVD 512

// ---- workspace layout ----
#define WS_COLSUM 262144
#define WS_LOSS   262656
#define WS_DIFFT_BYTES 1056768

// ---- output layout (f32 elements) ----
#define OUT_LOSS 33554432
#define OUT_W    33554433
#define OUT_S    33816577

__device__ inline u32 pkbf2(float a, float b) {
    __hip_bfloat162 h2 = __float22bfloat162_rn(make_float2(a, b));
    u32 r;
    __builtin_memcpy(&r, &h2, 4);
    return r;
}

__device__ inline void async16(const u16* g, u16* l) {
    __builtin_amdgcn_global_load_lds(
        (const __attribute__((address_space(1))) u32*)g,
        (__attribute__((address_space(3))) u32*)l, 16, 0, 0);
}

// =====================================================================
// K1: retrieved = k @ W.T   (128x128 tile, BK=64, bf16 MFMA 16x16x32)
// v3: SINGLE LDS buffer + register prefetch = same overlap as v2's
//     double-buffer (loads issued after b2 drain at next iter's b1,
//     covering the whole MFMA phase) but half the LDS -> 4 blocks/CU,
//     16 waves/CU.  XCD swizzle: xcd=bx&7 owns 64 rowtiles; the 4
//     ntile-sharers of each k row-tile are adjacent slots on one XCD
//     -> k re-reads become L2 hits.
// epilogue: write retrieved(fp32), loss partial, diffT(bf16, transposed)
// =====================================================================
#define PA 72    // A/B LDS pitch (shorts): conflict-free b128 frag reads
#define PT 136   // ldsT pitch (shorts): 16B-aligned rows, 2-way writes

__global__ __launch_bounds__(256, 4)
void k1_gemm1(const float* __restrict__ kmat, const float* __restrict__ vmat,
              const float* __restrict__ Wmat, float* __restrict__ out,
              float* __restrict__ ws, u16* __restrict__ diffT) {
    __shared__ u16 sm[18432];      // A: [0,9216) = 128x72, B: [9216,18432)
    __shared__ float lred[4];

    const int tid = threadIdx.x;
    const int bx = blockIdx.x;                  // 2048 blocks
    // XCD-aware swizzle: 8 XCDs x 256 slots; rowtile sharers co-XCD, adjacent
    const int xcd = bx & 7, slot = bx >> 3;
    const int rowtile = xcd * 64 + (slot >> 2), ntile = slot & 3;
    const long b0 = (long)rowtile * 128;
    const int vd0 = ntile * 128;
    const int wv = tid >> 6, lane = tid & 63;
    const int wm = wv & 1, wn = wv >> 1;
    const int col = lane & 15, kg = lane >> 4;

    const int srow = tid >> 4;                  // 0..15
    const int scol = (tid & 15) * 4;            // 0..60

    f32x4 acc[4][4] = {};

    const float* gA = kmat + (b0 + srow) * 512 + scol;
    const float* gB = Wmat + (long)(vd0 + srow) * 512 + scol;

    // prologue: load tile 0 into registers
    float4 ra[8], rb[8];
#pragma unroll
    for (int i = 0; i < 8; ++i) {
        ra[i] = *(const float4*)(gA + (long)i * 16 * 512);
        rb[i] = *(const float4*)(gB + (long)i * 16 * 512);
    }

    for (int it = 0; it < 8; ++it) {
        __syncthreads();   // b1: all waves done reading LDS for iter it-1
#pragma unroll
        for (int i = 0; i < 8; ++i) {
            int r = i * 16 + srow;
            *(uint2*)&sm[r * PA + scol] = make_uint2(pkbf2(ra[i].x, ra[i].y), pkbf2(ra[i].z, ra[i].w));
            *(uint2*)&sm[9216 + r * PA + scol] = make_uint2(pkbf2(rb[i].x, rb[i].y), pkbf2(rb[i].z, rb[i].w));
        }
        __syncthreads();   // b2: tile it visible
        // issue next tile's loads AFTER b2: they drain at next iter's b1,
        // i.e. they overlap the whole MFMA phase below.
        if (it < 7) {
            gA += 64; gB += 64;
#pragma unroll
            for (int i = 0; i < 8; ++i) {
                ra[i] = *(const float4*)(gA + (long)i * 16 * 512);
                rb[i] = *(const float4*)(gB + (long)i * 16 * 512);
            }
        }
#pragma unroll
        for (int kk = 0; kk < 2; ++kk) {
            bf16x8 af[4], bfr[4];
#pragma unroll
            for (int i = 0; i < 4; ++i)
                af[i] = *(const bf16x8*)&sm[(wm * 64 + i * 16 + col) * PA + kk * 32 + kg * 8];
#pragma unroll
            for (int j = 0; j < 4; ++j)
                bfr[j] = *(const bf16x8*)&sm[9216 + (wn * 64 + j * 16 + col) * PA + kk * 32 + kg * 8];
#pragma unroll
            for (int i = 0; i < 4; ++i)
#pragma unroll
                for (int j = 0; j < 4; ++j)
                    acc[i][j] = __builtin_amdgcn_mfma_f32_16x16x32_bf16(af[i], bfr[j], acc[i][j], 0, 0, 0);
        }
    }

    __syncthreads();   // protect LDS before ldsT overlay
    u16* smT = sm;     // [128 vd][PT] overlay, 34816 B

    float lossp = 0.f;
    const int rg = lane >> 4;
#pragma unroll
    for (int i = 0; i < 4; ++i) {
#pragma unroll
        for (int j = 0; j < 4; ++j) {
            int r0 = wm * 64 + i * 16 + rg * 4;
            int c  = wn * 64 + j * 16 + col;
            long gb = b0 + r0;
            float dd[4];
#pragma unroll
            for (int r = 0; r < 4; ++r) {
                float rv = acc[i][j][r];
                long gidx = (gb + r) * 512 + vd0 + c;
                out[gidx] = rv;
                float dv = rv - vmat[gidx];
                lossp += dv * dv;
                dd[r] = dv;
            }
            *(u32*)&smT[c * PT + r0]     = pkbf2(dd[0], dd[1]);
            *(u32*)&smT[c * PT + r0 + 2] = pkbf2(dd[2], dd[3]);
        }
    }

#pragma unroll
    for (int m = 32; m; m >>= 1) lossp += __shfl_xor(lossp, m);
    if (lane == 0) lred[wv] = lossp;
    __syncthreads();   // smT filled + lred ready
    if (tid == 0) atomicAdd(&ws[WS_LOSS], lred[0] + lred[1] + lred[2] + lred[3]);

    // diffT write-out: thread -> row c=tid>>1, half h=tid&1 (64 shorts)
    {
        const int c = tid >> 1, h = tid & 1;
        const u16* src = &smT[c * PT + h * 64];
        u16* dst = diffT + ((long)(vd0 + c) << 16) + b0 + h * 64;
#pragma unroll
        for (int q = 0; q < 8; ++q) {
            uint4 t4 = *(const uint4*)(src + q * 8);
            *(uint4*)(dst + q * 8) = t4;
        }
    }
}

// =====================================================================
// K2: grad_sum = diffT @ k  (per-tile 128x128, split-K=32 chunks of 2048)
// v3: A (diffT) double-buffered via global_load_lds; B (k fp32) register
//     prefetched + packed into a SINGLE LDS buffer (regs are its second
//     buffer). Two barriers per iter. LDS 51 KB -> 3 blocks/CU, 12 waves.
//     XCD swizzle: xcd owns 4 chunks; tile sharers (same k col-tile /
//     same diffT stripe) are adjacent slots on one XCD -> L2 hits.
// vd0==0 blocks also accumulate column sums of k for the gates.
// =====================================================================
__global__ __launch_bounds__(256, 3)
void k2_grad(const u16* __restrict__ diffT, const float* __restrict__ kmat,
             float* __restrict__ ws) {
    __shared__ u16 sm[25600];   // As dbuf: [0,8192)+[8192,16384) 128x64; Bs: [16384,25600) 128x72

    const int tid = threadIdx.x;
    const int bx = blockIdx.x;                  // 512 blocks
    // XCD-aware swizzle: 8 XCDs x 64 slots; xcd owns chunks [xcd*4, +4)
    const int xcd = bx & 7, slot = bx >> 3;
    const int chunk = xcd * 4 + (slot >> 4), tile = slot & 15;
    const int vd0 = (tile >> 2) * 128, kd0 = (tile & 3) * 128;
    const long b0 = (long)chunk * 2048;
    const int wv = tid >> 6, lane = tid & 63;
    const int wm = wv & 1, wn = wv >> 1;
    const int col = lane & 15, kg = lane >> 4;

    const int bcol = (tid & 63) * 2;            // column pair 0..126
    const int bq = wv * 16;                     // b quarter base

    f32x4 acc[4][4] = {};
    float cs0 = 0.f, cs1 = 0.f;

    const int rowb0 = wv * 32;
    // per-lane global base for A staging (q adds 8<<16, it adds 64)
    const u16* gAit = diffT + ((long)(vd0 + rowb0 + (lane >> 3)) << 16) + b0 + (lane & 7) * 8;
    const float* gk0 = kmat + (b0 + bq) * 512 + kd0 + bcol;

    float2 rB[16];
    // prologue: async-stage A(0) into buf0, load B(0) into registers
#pragma unroll
    for (int q = 0; q < 4; ++q)
        async16(gAit + ((long)(q * 8) << 16), &sm[(rowb0 + q * 8) * 64]);
#pragma unroll
    for (int i = 0; i < 16; ++i) rB[i] = *(const float2*)(gk0 + (long)i * 512);

    for (int it = 0; it < 32; ++it) {
        u16* As = sm + (it & 1) * 8192;
        u16* Bs = sm + 16384;
        __syncthreads();   // b1: prev MFMA reads done; As(it)+rB(it) drained
        // pack B(it) into Bs
        {
#pragma unroll
            for (int i = 0; i < 16; ++i) { cs0 += rB[i].x; cs1 += rB[i].y; }
            u32 p0[8], p1[8];
#pragma unroll
            for (int i = 0; i < 8; ++i) {
                p0[i] = pkbf2(rB[2 * i].x, rB[2 * i + 1].x);
                p1[i] = pkbf2(rB[2 * i].y, rB[2 * i + 1].y);
            }
            *(uint4*)&Bs[bcol * PA + bq]           = make_uint4(p0[0], p0[1], p0[2], p0[3]);
            *(uint4*)&Bs[bcol * PA + bq + 8]       = make_uint4(p0[4], p0[5], p0[6], p0[7]);
            *(uint4*)&Bs[(bcol + 1) * PA + bq]     = make_uint4(p1[0], p1[1], p1[2], p1[3]);
            *(uint4*)&Bs[(bcol + 1) * PA + bq + 8] = make_uint4(p1[4], p1[5], p1[6], p1[7]);
        }
        __syncthreads();   // b2: Bs(it) visible (As(it) already at b1)
        // issue next tile's staging AFTER b2 -> overlaps MFMAs below,
        // drains only at next iter's b1.
        if (it < 31) {
            u16* An = sm + ((it + 1) & 1) * 8192;
            const u16* gan = gAit + (it + 1) * 64;
#pragma unroll
            for (int q = 0; q < 4; ++q)
                async16(gan + ((long)(q * 8) << 16), &An[(rowb0 + q * 8) * 64]);
            const float* gkn = gk0 + (long)(it + 1) * 64 * 512;
#pragma unroll
            for (int i = 0; i < 16; ++i) rB[i] = *(const float2*)(gkn + (long)i * 512);
        }
#pragma unroll
        for (int kk = 0; kk < 2; ++kk) {
            bf16x8 af[4], bfr[4];
#pragma unroll
            for (int i = 0; i < 4; ++i)
                af[i] = *(const bf16x8*)&As[(wm * 64 + i * 16 + col) * 64 + kk * 32 + kg * 8];
#pragma unroll
            for (int j = 0; j < 4; ++j)
                bfr[j] = *(const bf16x8*)&Bs[(wn * 64 + j * 16 + col) * PA + kk * 32 + kg * 8];
#pragma unroll
            for (int i = 0; i < 4; ++i)
#pragma unroll
                for (int j = 0; j < 4; ++j)
                    acc[i][j] = __builtin_amdgcn_mfma_f32_16x16x32_bf16(af[i], bfr[j], acc[i][j], 0, 0, 0);
        }
    }

    // grad accumulation
    const int rg = lane >> 4;
#pragma unroll
    for (int i = 0; i < 4; ++i)
#pragma unroll
        for (int j = 0; j < 4; ++j)
#pragma unroll
            for (int r = 0; r < 4; ++r) {
                int vd = vd0 + wm * 64 + i * 16 + rg * 4 + r;
                int kd = kd0 + wn * 64 + j * 16 + col;
                atomicAdd(&ws[vd * 512 + kd], acc[i][j][r]);
            }

    // column sums (only one vd-stripe contributes; others read same k but skip)
    if (vd0 == 0) {
        __syncthreads();
        float* cred = (float*)sm;   // [128][4]
        cred[bcol * 4 + wv] = cs0;
        cred[(bcol + 1) * 4 + wv] = cs1;
        __syncthreads();
        if (tid < 128) {
            float s = cred[tid * 4] + cred[tid * 4 + 1] + cred[tid * 4 + 2] + cred[tid * 4 + 3];
            atomicAdd(&ws[WS_COLSUM + kd0 + tid], s);
        }
    }
}

// =====================================================================
// K3: gates + new_W/new_S + loss finalize
// =====================================================================
__global__ __launch_bounds__(256)
void k3_final(const float* __restrict__ Wmat, const float* __restrict__ Smat,
              const float* __restrict__ gw, const float* __restrict__ gb,
              const float* __restrict__ ws, float* __restrict__ out) {
    __shared__ float gates[3];
    const int tid = threadIdx.x;
    if (tid < 64) {
        float d0 = 0.f, d1 = 0.f, d2 = 0.f;
#pragma unroll
        for (int i = 0; i < 8; ++i) {
            int kd = i * 64 + tid;
            float km = ws[WS_COLSUM + kd] * (1.0f / 65536.0f);
            d0 += gw[kd] * km;
            d1 += gw[512 + kd] * km;
            d2 += gw[1024 + kd] * km;
        }
#pragma unroll
        for (int m = 32; m; m >>= 1) {
            d0 += __shfl_xor(d0, m);
            d1 += __shfl_xor(d1, m);
            d2 += __shfl_xor(d2, m);
        }
        if (tid == 0) {
            gates[0] = 1.f / (1.f + __expf(-(d0 + gb[0])));   // alpha
            gates[1] = 1.f / (1.f + __expf(-(d1 + gb[1])));   // eta
            gates[2] = 1.f / (1.f + __expf(-(d2 + gb[2])));   // theta
        }
    }
    __syncthreads();
    const float alpha = gates[0], eta = gates[1], theta = gates[2];
    const int i = blockIdx.x * 256 + tid;
    float g = ws[i] * 5.9604644775390625e-8f;      // 2/(B*VD)
    float ns = eta * Smat[i] - theta * g;
    out[OUT_S + i] = ns;
    out[OUT_W + i] = (1.f - alpha) * Wmat[i] + ns;
    if (blockIdx.x == 0 && tid == 0)
        out[OUT_LOSS] = ws[WS_LOSS] * 2.98023223876953125e-8f;  // 1/(B*VD)
}

extern "C" void kernel_launch(void* const* d_in, const int* in_sizes, int n_in,
                              void* d_out, int out_size, void* d_ws, size_t ws_size,
                              hipStream_t stream) {
    const float* k  = (const float*)d_in[0];
    const float* v  = (const float*)d_in[1];
    const float* W  = (const float*)d_in[2];
    const float* S  = (const float*)d_in[3];
    const float* gw = (const float*)d_in[4];
    const float* gb = (const float*)d_in[5];
    float* out = (float*)d_out;
    float* ws  = (float*)d_ws;
    u16* diffT = (u16*)((char*)d_ws + WS_DIFFT_BYTES);

    // zero grad sums + colsum + loss (ws is re-poisoned to 0xAA each launch)
    hipMemsetAsync(d_ws, 0, (WS_LOSS + 1) * sizeof(float), stream);

    hipLaunchKernelGGL(k1_gemm1, dim3(2048), dim3(256), 0, stream, k, v, W, out, ws, diffT);
    hipLaunchKernelGGL(k2_grad,  dim3(512),  dim3(256), 0, stream, diffT, k, ws);
    hipLaunchKernelGGL(k3_final, dim3(1024), dim3(256), 0, stream, W, S, gw, gb, ws, out);
}

// Round 5
// 490.583 us; speedup vs baseline: 1.0648x; 1.0648x over previous
//
#include <hip/hip_runtime.h>
#include <hip/hip_bf16.h>

typedef __attribute__((ext_vector_type(8))) short bf16x8;
typedef __attribute__((ext_vector_type(4))) float f32x4;
typedef unsigned int u32;
typedef unsigned short u16;

#define NB 65536
#define NKD 512
#define NVD 512

// ---- workspace layout ----
#define WS_COLSUM 262144
#define WS_LOSS   262656
#define WS_DIFFT_BYTES 1056768

// ---- output layout (f32 elements) ----
#define OUT_LOSS 33554432
#define OUT_W    33554433
#define OUT_S    33816577

__device__ inline u32 pkbf2(float a, float b) {
    __hip_bfloat162 h2 = __float22bfloat162_rn(make_float2(a, b));
    u32 r;
    __builtin_memcpy(&r, &h2, 4);
    return r;
}

__device__ inline void async16(const u16* g, u16* l) {
    __builtin_amdgcn_global_load_lds(
        (const __attribute__((address_space(1))) u32*)g,
        (__attribute__((address_space(3))) u32*)l, 16, 0, 0);
}

// =====================================================================
// K1: retrieved = k @ W.T   (128x128 tile, BK=64, bf16 MFMA 16x16x32)
// v4: identical to v3 EXCEPT __launch_bounds__(256,3): unified reg
//     budget 170/wave fits 88 VGPR + 64 AGPR, so the register prefetch
//     (the software pipeline) survives, AND LDS 37 KB allows 3 blocks/CU
//     = 12 waves/CU.  v3's (256,4) capped the budget at 128 and the
//     compiler sank the prefetch loads (VGPR_Count fell to 64) -> serial.
//     XCD swizzle kept (measured: FETCH 332->185 MB).
// epilogue: write retrieved(fp32), loss partial, diffT(bf16, transposed)
// =====================================================================
#define PA 72    // A/B LDS pitch (shorts): conflict-free b128 frag reads
#define PT 136   // ldsT pitch (shorts): 16B-aligned rows, 2-way writes

__global__ __launch_bounds__(256, 3)
void k1_gemm1(const float* __restrict__ kmat, const float* __restrict__ vmat,
              const float* __restrict__ Wmat, float* __restrict__ out,
              float* __restrict__ ws, u16* __restrict__ diffT) {
    __shared__ u16 sm[18432];      // A: [0,9216) = 128x72, B: [9216,18432)
    __shared__ float lred[4];

    const int tid = threadIdx.x;
    const int bx = blockIdx.x;                  // 2048 blocks
    // XCD-aware swizzle: 8 XCDs x 256 slots; rowtile sharers co-XCD, adjacent
    const int xcd = bx & 7, slot = bx >> 3;
    const int rowtile = xcd * 64 + (slot >> 2), ntile = slot & 3;
    const long b0 = (long)rowtile * 128;
    const int vd0 = ntile * 128;
    const int wv = tid >> 6, lane = tid & 63;
    const int wm = wv & 1, wn = wv >> 1;
    const int col = lane & 15, kg = lane >> 4;

    const int srow = tid >> 4;                  // 0..15
    const int scol = (tid & 15) * 4;            // 0..60

    f32x4 acc[4][4] = {};

    const float* gA = kmat + (b0 + srow) * 512 + scol;
    const float* gB = Wmat + (long)(vd0 + srow) * 512 + scol;

    // prologue: load tile 0 into registers
    float4 ra[8], rb[8];
#pragma unroll
    for (int i = 0; i < 8; ++i) {
        ra[i] = *(const float4*)(gA + (long)i * 16 * 512);
        rb[i] = *(const float4*)(gB + (long)i * 16 * 512);
    }

    for (int it = 0; it < 8; ++it) {
        __syncthreads();   // b1: all waves done reading LDS for iter it-1
#pragma unroll
        for (int i = 0; i < 8; ++i) {
            int r = i * 16 + srow;
            *(uint2*)&sm[r * PA + scol] = make_uint2(pkbf2(ra[i].x, ra[i].y), pkbf2(ra[i].z, ra[i].w));
            *(uint2*)&sm[9216 + r * PA + scol] = make_uint2(pkbf2(rb[i].x, rb[i].y), pkbf2(rb[i].z, rb[i].w));
        }
        __syncthreads();   // b2: tile it visible
        // issue next tile's loads AFTER b2: they drain at next iter's b1,
        // i.e. they overlap the whole MFMA phase below.
        if (it < 7) {
            gA += 64; gB += 64;
#pragma unroll
            for (int i = 0; i < 8; ++i) {
                ra[i] = *(const float4*)(gA + (long)i * 16 * 512);
                rb[i] = *(const float4*)(gB + (long)i * 16 * 512);
            }
        }
#pragma unroll
        for (int kk = 0; kk < 2; ++kk) {
            bf16x8 af[4], bfr[4];
#pragma unroll
            for (int i = 0; i < 4; ++i)
                af[i] = *(const bf16x8*)&sm[(wm * 64 + i * 16 + col) * PA + kk * 32 + kg * 8];
#pragma unroll
            for (int j = 0; j < 4; ++j)
                bfr[j] = *(const bf16x8*)&sm[9216 + (wn * 64 + j * 16 + col) * PA + kk * 32 + kg * 8];
#pragma unroll
            for (int i = 0; i < 4; ++i)
#pragma unroll
                for (int j = 0; j < 4; ++j)
                    acc[i][j] = __builtin_amdgcn_mfma_f32_16x16x32_bf16(af[i], bfr[j], acc[i][j], 0, 0, 0);
        }
    }

    __syncthreads();   // protect LDS before ldsT overlay
    u16* smT = sm;     // [128 vd][PT] overlay, 34816 B

    float lossp = 0.f;
    const int rg = lane >> 4;
#pragma unroll
    for (int i = 0; i < 4; ++i) {
#pragma unroll
        for (int j = 0; j < 4; ++j) {
            int r0 = wm * 64 + i * 16 + rg * 4;
            int c  = wn * 64 + j * 16 + col;
            long gb = b0 + r0;
            float dd[4];
#pragma unroll
            for (int r = 0; r < 4; ++r) {
                float rv = acc[i][j][r];
                long gidx = (gb + r) * 512 + vd0 + c;
                out[gidx] = rv;
                float dv = rv - vmat[gidx];
                lossp += dv * dv;
                dd[r] = dv;
            }
            *(u32*)&smT[c * PT + r0]     = pkbf2(dd[0], dd[1]);
            *(u32*)&smT[c * PT + r0 + 2] = pkbf2(dd[2], dd[3]);
        }
    }

#pragma unroll
    for (int m = 32; m; m >>= 1) lossp += __shfl_xor(lossp, m);
    if (lane == 0) lred[wv] = lossp;
    __syncthreads();   // smT filled + lred ready
    if (tid == 0) atomicAdd(&ws[WS_LOSS], lred[0] + lred[1] + lred[2] + lred[3]);

    // diffT write-out: thread -> row c=tid>>1, half h=tid&1 (64 shorts)
    {
        const int c = tid >> 1, h = tid & 1;
        const u16* src = &smT[c * PT + h * 64];
        u16* dst = diffT + ((long)(vd0 + c) << 16) + b0 + h * 64;
#pragma unroll
        for (int q = 0; q < 8; ++q) {
            uint4 t4 = *(const uint4*)(src + q * 8);
            *(uint4*)(dst + q * 8) = t4;
        }
    }
}

// =====================================================================
// K2: grad_sum = diffT @ k  (per-tile 128x128, split-K=32 chunks of 2048)
// v4: unchanged from v3 (its prefetch fits in the (256,3) budget:
//     ~62 VGPR + 64 AGPR = 126 <= 170). A (diffT) double-buffered via
//     global_load_lds; B (k fp32) register prefetched + packed into a
//     single LDS buffer. XCD chunk swizzle.
// vd0==0 blocks also accumulate column sums of k for the gates.
// =====================================================================
__global__ __launch_bounds__(256, 3)
void k2_grad(const u16* __restrict__ diffT, const float* __restrict__ kmat,
             float* __restrict__ ws) {
    __shared__ u16 sm[25600];   // As dbuf: [0,8192)+[8192,16384) 128x64; Bs: [16384,25600) 128x72

    const int tid = threadIdx.x;
    const int bx = blockIdx.x;                  // 512 blocks
    // XCD-aware swizzle: 8 XCDs x 64 slots; xcd owns chunks [xcd*4, +4)
    const int xcd = bx & 7, slot = bx >> 3;
    const int chunk = xcd * 4 + (slot >> 4), tile = slot & 15;
    const int vd0 = (tile >> 2) * 128, kd0 = (tile & 3) * 128;
    const long b0 = (long)chunk * 2048;
    const int wv = tid >> 6, lane = tid & 63;
    const int wm = wv & 1, wn = wv >> 1;
    const int col = lane & 15, kg = lane >> 4;

    const int bcol = (tid & 63) * 2;            // column pair 0..126
    const int bq = wv * 16;                     // b quarter base

    f32x4 acc[4][4] = {};
    float cs0 = 0.f, cs1 = 0.f;

    const int rowb0 = wv * 32;
    // per-lane global base for A staging (q adds 8<<16, it adds 64)
    const u16* gAit = diffT + ((long)(vd0 + rowb0 + (lane >> 3)) << 16) + b0 + (lane & 7) * 8;
    const float* gk0 = kmat + (b0 + bq) * 512 + kd0 + bcol;

    float2 rB[16];
    // prologue: async-stage A(0) into buf0, load B(0) into registers
#pragma unroll
    for (int q = 0; q < 4; ++q)
        async16(gAit + ((long)(q * 8) << 16), &sm[(rowb0 + q * 8) * 64]);
#pragma unroll
    for (int i = 0; i < 16; ++i) rB[i] = *(const float2*)(gk0 + (long)i * 512);

    for (int it = 0; it < 32; ++it) {
        u16* As = sm + (it & 1) * 8192;
        u16* Bs = sm + 16384;
        __syncthreads();   // b1: prev MFMA reads done; As(it)+rB(it) drained
        // pack B(it) into Bs
        {
#pragma unroll
            for (int i = 0; i < 16; ++i) { cs0 += rB[i].x; cs1 += rB[i].y; }
            u32 p0[8], p1[8];
#pragma unroll
            for (int i = 0; i < 8; ++i) {
                p0[i] = pkbf2(rB[2 * i].x, rB[2 * i + 1].x);
                p1[i] = pkbf2(rB[2 * i].y, rB[2 * i + 1].y);
            }
            *(uint4*)&Bs[bcol * PA + bq]           = make_uint4(p0[0], p0[1], p0[2], p0[3]);
            *(uint4*)&Bs[bcol * PA + bq + 8]       = make_uint4(p0[4], p0[5], p0[6], p0[7]);
            *(uint4*)&Bs[(bcol + 1) * PA + bq]     = make_uint4(p1[0], p1[1], p1[2], p1[3]);
            *(uint4*)&Bs[(bcol + 1) * PA + bq + 8] = make_uint4(p1[4], p1[5], p1[6], p1[7]);
        }
        __syncthreads();   // b2: Bs(it) visible (As(it) already at b1)
        // issue next tile's staging AFTER b2 -> overlaps MFMAs below,
        // drains only at next iter's b1.
        if (it < 31) {
            u16* An = sm + ((it + 1) & 1) * 8192;
            const u16* gan = gAit + (it + 1) * 64;
#pragma unroll
            for (int q = 0; q < 4; ++q)
                async16(gan + ((long)(q * 8) << 16), &An[(rowb0 + q * 8) * 64]);
            const float* gkn = gk0 + (long)(it + 1) * 64 * 512;
#pragma unroll
            for (int i = 0; i < 16; ++i) rB[i] = *(const float2*)(gkn + (long)i * 512);
        }
#pragma unroll
        for (int kk = 0; kk < 2; ++kk) {
            bf16x8 af[4], bfr[4];
#pragma unroll
            for (int i = 0; i < 4; ++i)
                af[i] = *(const bf16x8*)&As[(wm * 64 + i * 16 + col) * 64 + kk * 32 + kg * 8];
#pragma unroll
            for (int j = 0; j < 4; ++j)
                bfr[j] = *(const bf16x8*)&Bs[(wn * 64 + j * 16 + col) * PA + kk * 32 + kg * 8];
#pragma unroll
            for (int i = 0; i < 4; ++i)
#pragma unroll
                for (int j = 0; j < 4; ++j)
                    acc[i][j] = __builtin_amdgcn_mfma_f32_16x16x32_bf16(af[i], bfr[j], acc[i][j], 0, 0, 0);
        }
    }

    // grad accumulation
    const int rg = lane >> 4;
#pragma unroll
    for (int i = 0; i < 4; ++i)
#pragma unroll
        for (int j = 0; j < 4; ++j)
#pragma unroll
            for (int r = 0; r < 4; ++r) {
                int vd = vd0 + wm * 64 + i * 16 + rg * 4 + r;
                int kd = kd0 + wn * 64 + j * 16 + col;
                atomicAdd(&ws[vd * 512 + kd], acc[i][j][r]);
            }

    // column sums (only one vd-stripe contributes; others read same k but skip)
    if (vd0 == 0) {
        __syncthreads();
        float* cred = (float*)sm;   // [128][4]
        cred[bcol * 4 + wv] = cs0;
        cred[(bcol + 1) * 4 + wv] = cs1;
        __syncthreads();
        if (tid < 128) {
            float s = cred[tid * 4] + cred[tid * 4 + 1] + cred[tid * 4 + 2] + cred[tid * 4 + 3];
            atomicAdd(&ws[WS_COLSUM + kd0 + tid], s);
        }
    }
}

// =====================================================================
// K3: gates + new_W/new_S + loss finalize
// =====================================================================
__global__ __launch_bounds__(256)
void k3_final(const float* __restrict__ Wmat, const float* __restrict__ Smat,
              const float* __restrict__ gw, const float* __restrict__ gb,
              const float* __restrict__ ws, float* __restrict__ out) {
    __shared__ float gates[3];
    const int tid = threadIdx.x;
    if (tid < 64) {
        float d0 = 0.f, d1 = 0.f, d2 = 0.f;
#pragma unroll
        for (int i = 0; i < 8; ++i) {
            int kd = i * 64 + tid;
            float km = ws[WS_COLSUM + kd] * (1.0f / 65536.0f);
            d0 += gw[kd] * km;
            d1 += gw[512 + kd] * km;
            d2 += gw[1024 + kd] * km;
        }
#pragma unroll
        for (int m = 32; m; m >>= 1) {
            d0 += __shfl_xor(d0, m);
            d1 += __shfl_xor(d1, m);
            d2 += __shfl_xor(d2, m);
        }
        if (tid == 0) {
            gates[0] = 1.f / (1.f + __expf(-(d0 + gb[0])));   // alpha
            gates[1] = 1.f / (1.f + __expf(-(d1 + gb[1])));   // eta
            gates[2] = 1.f / (1.f + __expf(-(d2 + gb[2])));   // theta
        }
    }
    __syncthreads();
    const float alpha = gates[0], eta = gates[1], theta = gates[2];
    const int i = blockIdx.x * 256 + tid;
    float g = ws[i] * 5.9604644775390625e-8f;      // 2/(B*VD)
    float ns = eta * Smat[i] - theta * g;
    out[OUT_S + i] = ns;
    out[OUT_W + i] = (1.f - alpha) * Wmat[i] + ns;
    if (blockIdx.x == 0 && tid == 0)
        out[OUT_LOSS] = ws[WS_LOSS] * 2.98023223876953125e-8f;  // 1/(B*VD)
}

extern "C" void kernel_launch(void* const* d_in, const int* in_sizes, int n_in,
                              void* d_out, int out_size, void* d_ws, size_t ws_size,
                              hipStream_t stream) {
    const float* k  = (const float*)d_in[0];
    const float* v  = (const float*)d_in[1];
    const float* W  = (const float*)d_in[2];
    const float* S  = (const float*)d_in[3];
    const float* gw = (const float*)d_in[4];
    const float* gb = (const float*)d_in[5];
    float* out = (float*)d_out;
    float* ws  = (float*)d_ws;
    u16* diffT = (u16*)((char*)d_ws + WS_DIFFT_BYTES);

    // zero grad sums + colsum + loss (ws is re-poisoned to 0xAA each launch)
    hipMemsetAsync(d_ws, 0, (WS_LOSS + 1) * sizeof(float), stream);

    hipLaunchKernelGGL(k1_gemm1, dim3(2048), dim3(256), 0, stream, k, v, W, out, ws, diffT);
    hipLaunchKernelGGL(k2_grad,  dim3(512),  dim3(256), 0, stream, diffT, k, ws);
    hipLaunchKernelGGL(k3_final, dim3(1024), dim3(256), 0, stream, W, S, gw, gb, ws, out);
}